// Round 5
// baseline (106.819 us; speedup 1.0000x reference)
//
#include <hip/hip_runtime.h>
#include <math.h>

// Multitask loss, single fused kernel.
//   loss = mean(bce(pb,tb)) + mean(bce(pt,tt)) + mean(CE(ps,ts))
//        + mean((pb>0)^(pt[:,0]>0)) + mean((pb>0)^(argmax(ps)>0))
// bce(x,y) = max(x,0) - x*y + log1p(exp(-|x|))
//
// Structure (R2 lane-stride-1 pattern, measured best):
//  - thread-per-row, 2048 blocks x 256 thr, 4 grid-stride iterations
//  - pt/tt staged per-chunk through LDS with coalesced float4 loads
//    (direct version = 10 strided scalar dwords/row, 5x the line requests)
//  - ps read directly: 4x float4, each lane owns its 64B row line
//  - finish: per-block sum -> fixed-point (x 2^32) integer atomicAdd
//    (order-independent => deterministic) + last-block writes out[0].
//    ws[0..7]=acc(u64), ws[8..11]=counter(u32); memsetAsync zeroes per call.

#define NBLOCKS 2048
#define NTHREADS 256
#define FIXED_SCALE 4294967296.0   // 2^32

__device__ __forceinline__ float bce_term(float x, float y) {
    // max(x,0) - x*y + log1p(exp(-|x|)); log arg in (1,2] -> no cancellation
    return fmaxf(x, 0.0f) - x * y + __logf(1.0f + __expf(-fabsf(x)));
}

__global__ __launch_bounds__(NTHREADS) void mtl_kernel(
    const float* __restrict__ pb,   // [B]    y_pred_binary
    const float* __restrict__ pt,   // [B,5]  y_pred_type
    const float* __restrict__ ps,   // [B,16] y_pred_source
    const float* __restrict__ tb,   // [B]    y_true_binary
    const float* __restrict__ tt,   // [B,5]  y_true_type
    const int*   __restrict__ ts,   // [B]    y_true_source
    unsigned long long* __restrict__ acc_fixed,  // zeroed each call
    unsigned int* __restrict__ cnt,              // zeroed each call
    float* __restrict__ out, int B)
{
    __shared__ __align__(16) float lds_pt[5 * NTHREADS];
    __shared__ __align__(16) float lds_tt[5 * NTHREADS];
    __shared__ double smem[NTHREADS / 64];

    const int t = threadIdx.x;
    const int stride = NBLOCKS * NTHREADS;
    const int iters = (B + stride - 1) / stride;   // 4 for B = 2^21

    float acc = 0.0f;  // <= 4 rows (~30 max each): f32 exact enough (R2: absmax 0)

    for (int k = 0; k < iters; ++k) {
        const int R0 = k * stride + blockIdx.x * NTHREADS;  // chunk base row

        // ---- stage pt/tt rows [R0, R0+256) into LDS, coalesced float4 ----
        if (R0 < B) {
            const int nrows = min(NTHREADS, B - R0);
            if (nrows == NTHREADS) {
                // 320 float4 per array; thread t takes j=t and (t<64) j=256+t
                const float4* p4 = reinterpret_cast<const float4*>(pt + (size_t)R0 * 5);
                const float4* t4 = reinterpret_cast<const float4*>(tt + (size_t)R0 * 5);
                float4* lp4 = reinterpret_cast<float4*>(lds_pt);
                float4* lt4 = reinterpret_cast<float4*>(lds_tt);
                const float4 a0 = p4[t];
                const float4 b0 = t4[t];
                lp4[t] = a0;
                lt4[t] = b0;
                if (t < 5 * NTHREADS / 4 - NTHREADS) {  // t < 64
                    const float4 a1 = p4[NTHREADS + t];
                    const float4 b1 = t4[NTHREADS + t];
                    lp4[NTHREADS + t] = a1;
                    lt4[NTHREADS + t] = b1;
                }
            } else {
                for (int e = t; e < nrows * 5; e += NTHREADS) {
                    lds_pt[e] = pt[(size_t)R0 * 5 + e];
                    lds_tt[e] = tt[(size_t)R0 * 5 + e];
                }
            }
        }
        __syncthreads();

        // ---- per-row compute ----
        const int r = R0 + t;
        if (r < B) {
            const float xb = pb[r];
            const float yb = tb[r];
            const int   tg = ts[r];

            // task A
            float c = fmaxf(xb, 0.0f) - xb * yb + __logf(1.0f + __expf(-fabsf(xb)));

            // task B from LDS (stride-5 reads: gcd(5,32)=1 -> 2 lanes/bank, free)
            float t0 = 0.0f;
            float st = 0.0f;
            #pragma unroll
            for (int j = 0; j < 5; ++j) {
                const float x = lds_pt[t * 5 + j];
                const float y = lds_tt[t * 5 + j];
                if (j == 0) t0 = x;
                st += bce_term(x, y);
            }
            c += st * 0.2f;

            // task C: 16-way CE; lane owns its 64B row line
            float xs[16];  // static indexing only
            const float4* ps4 = reinterpret_cast<const float4*>(ps + (size_t)r * 16);
            #pragma unroll
            for (int q = 0; q < 4; ++q) {
                const float4 v = ps4[q];
                xs[q * 4 + 0] = v.x;
                xs[q * 4 + 1] = v.y;
                xs[q * 4 + 2] = v.z;
                xs[q * 4 + 3] = v.w;
            }
            // argmax>0 <=> max(xs[1..15]) > xs[0] (strict, first-occurrence ties)
            float m15 = xs[1];
            #pragma unroll
            for (int j = 2; j < 16; ++j) m15 = fmaxf(m15, xs[j]);
            const float m = fmaxf(xs[0], m15);

            float se = 0.0f;
            float xt = 0.0f;  // xs[tg] via unrolled cndmask chain
            #pragma unroll
            for (int j = 0; j < 16; ++j) {
                se += __expf(xs[j] - m);
                xt = (j == tg) ? xs[j] : xt;
            }
            c += m + __logf(se) - xt;  // -logp[tg]

            const bool bc = xb > 0.0f;
            c += (bc != (t0 > 0.0f)) ? 1.0f : 0.0f;
            c += (bc != (m15 > xs[0])) ? 1.0f : 0.0f;

            acc += c;
        }
        __syncthreads();  // protect LDS before next-chunk staging
    }

    // ---- block reduction (wave shfl f32, cross-wave via LDS) ----
    float a = acc;
    #pragma unroll
    for (int off = 32; off > 0; off >>= 1)
        a += __shfl_down(a, off, 64);
    const int lane = t & 63;
    const int wave = t >> 6;
    if (lane == 0) smem[wave] = (double)a;
    __syncthreads();

    // ---- deterministic fixed-point global accumulate + last-block finish ----
    if (t == 0) {
        double s = 0.0;
        #pragma unroll
        for (int w = 0; w < NTHREADS / 64; ++w) s += smem[w];
        const unsigned long long v =
            (unsigned long long)(long long)llrint(s * FIXED_SCALE);
        atomicAdd(acc_fixed, v);            // integer add: order-independent
        __threadfence();
        const unsigned int done = atomicAdd(cnt, 1u);
        if (done == (unsigned int)(gridDim.x - 1)) {
            __threadfence();
            const unsigned long long tot = atomicAdd(acc_fixed, 0ull);
            out[0] = (float)((double)(long long)tot * (1.0 / FIXED_SCALE)
                             / (double)B);
        }
    }
}

extern "C" void kernel_launch(void* const* d_in, const int* in_sizes, int n_in,
                              void* d_out, int out_size, void* d_ws, size_t ws_size,
                              hipStream_t stream) {
    const float* pb = (const float*)d_in[0];
    const float* pt = (const float*)d_in[1];
    const float* ps = (const float*)d_in[2];
    const float* tb = (const float*)d_in[3];
    const float* tt = (const float*)d_in[4];
    const int*   ts = (const int*)d_in[5];
    float* out = (float*)d_out;
    const int B = in_sizes[0];

    unsigned long long* acc_fixed = (unsigned long long*)d_ws;
    unsigned int* cnt = (unsigned int*)((char*)d_ws + 8);

    hipMemsetAsync(d_ws, 0, 16, stream);  // zero acc + counter each call
    mtl_kernel<<<NBLOCKS, NTHREADS, 0, stream>>>(pb, pt, ps, tb, tt, ts,
                                                 acc_fixed, cnt, out, B);
}

// Round 6
// 48.656 us; speedup vs baseline: 2.1954x; 2.1954x over previous
//
#include <hip/hip_runtime.h>
#include <math.h>

// Multitask loss, quad-cooperative (4 lanes per row):
//   loss = mean(bce(pb,tb)) + mean(bce(pt,tt)) + mean(CE(ps,ts))
//        + mean((pb>0)^(pt[:,0]>0)) + mean((pb>0)^(argmax(ps)>0))
// bce(x,y) = max(x,0) - x*y + log1p(exp(-|x|))
//
// Why quads: R2's thread-per-row issued ~472 cache-line requests per 64 rows
// (ps float4 at 64B lane-stride = 64 lines/instr; pt/tt scalar = 20 lines/instr)
// vs the 116 minimum -> TA/L1 request-rate bound (~25us). Quad layout:
//   ps: one float4/lane at 16B lane-stride -> 16 lines/instr, min requests
//   pt/tt: lane q takes elem q, lane 0 also elem 4 -> 2 instrs, 10 lines
//   pb/tb: lane 0 only; ts: all quad lanes (same-line merge)
// Softmax max/sumexp/select reduced over the quad via __shfl_xor 1/2
// (quad_perm DPP). Lane 0 finishes CE + task A + XOR terms.
// Fast intrinsics (__expf/__logf): tolerance 0.117 absmax on a ~5.8 scalar.

#define NBLOCKS 2048
#define NTHREADS 256

__device__ __forceinline__ float bce_term(float x, float y) {
    // max(x,0) - x*y + log1p(exp(-|x|)); log arg in (1,2] -> no cancellation
    return fmaxf(x, 0.0f) - x * y + __logf(1.0f + __expf(-fabsf(x)));
}

__device__ __forceinline__ float qmax(float v) {
    v = fmaxf(v, __shfl_xor(v, 1));
    v = fmaxf(v, __shfl_xor(v, 2));
    return v;
}
__device__ __forceinline__ float qsum(float v) {
    v += __shfl_xor(v, 1);
    v += __shfl_xor(v, 2);
    return v;
}

__global__ __launch_bounds__(NTHREADS) void mtl_partial_kernel(
    const float* __restrict__ pb,   // [B]    y_pred_binary
    const float* __restrict__ pt,   // [B,5]  y_pred_type
    const float* __restrict__ ps,   // [B,16] y_pred_source
    const float* __restrict__ tb,   // [B]    y_true_binary
    const float* __restrict__ tt,   // [B,5]  y_true_type
    const int*   __restrict__ ts,   // [B]    y_true_source
    double* __restrict__ partial,   // [NBLOCKS]
    int B)
{
    const int t  = threadIdx.x;
    const int q  = t & 3;                 // quarter index within the quad
    const bool l0 = (q == 0);
    const int gid0    = (blockIdx.x * NTHREADS + t) >> 2;   // row of this quad
    const int ngroups = (NBLOCKS * NTHREADS) >> 2;          // rows per grid-iter

    float acc = 0.0f;  // 16 iters, |terms| small: f32 exact enough (R2: absmax 0)

    for (int r = gid0; r < B; r += ngroups) {
        // ---- loads (per quad: 1x float4 ps, 2+2 scalars pt/tt, row scalars) ----
        const float4 v4 = reinterpret_cast<const float4*>(ps)[(size_t)r * 4 + q];
        const int   tg  = ts[r];                       // all quad lanes: same line
        const float ptj = pt[(size_t)r * 5 + q];
        const float ttj = tt[(size_t)r * 5 + q];
        float xb = 0.0f, yb = 0.0f, pt4 = 0.0f, tt4 = 0.0f;
        if (l0) {
            xb  = pb[r];
            yb  = tb[r];
            pt4 = pt[(size_t)r * 5 + 4];
            tt4 = tt[(size_t)r * 5 + 4];
        }

        // ---- task B: BCE partials stay per-lane (global mean is separable) ----
        float bsum = bce_term(ptj, ttj);
        if (l0) bsum += bce_term(pt4, tt4);
        acc += bsum * 0.2f;

        // ---- task C: quad-cooperative 16-way log-softmax ----
        const float x0 = v4.x, x1 = v4.y, x2 = v4.z, x3 = v4.w;
        const float lmax_all = fmaxf(fmaxf(x0, x1), fmaxf(x2, x3));
        const float lmax_ex0 = l0 ? fmaxf(fmaxf(x1, x2), x3) : lmax_all;
        const float m   = qmax(lmax_all);   // max over all 16
        const float m15 = qmax(lmax_ex0);   // max over elems 1..15

        const float e = __expf(x0 - m) + __expf(x1 - m) +
                        __expf(x2 - m) + __expf(x3 - m);
        const float se = qsum(e);

        float xtl = 0.0f;                   // xs[tg]: owning lane contributes
        if ((tg >> 2) == q) {
            const int k = tg & 3;
            xtl = (k == 0) ? x0 : (k == 1) ? x1 : (k == 2) ? x2 : x3;
        }
        const float xt = qsum(xtl);

        // ---- lane 0 finishes the row: task A + CE + XOR terms ----
        if (l0) {
            float c = fmaxf(xb, 0.0f) - xb * yb +
                      __logf(1.0f + __expf(-fabsf(xb)));
            c += m + __logf(se) - xt;       // -logp[tg]
            const bool bc = xb > 0.0f;
            c += (bc != (ptj > 0.0f)) ? 1.0f : 0.0f;     // ptj = pt[5r] here
            c += (bc != (m15 > x0)) ? 1.0f : 0.0f;       // argmax>0, strict
            acc += c;
        }
    }

    // ---- block reduction (wave shfl in f32, cross-wave via LDS) ----
    float a = acc;
    #pragma unroll
    for (int off = 32; off > 0; off >>= 1)
        a += __shfl_down(a, off, 64);

    __shared__ double smem[NTHREADS / 64];
    const int lane = t & 63;
    const int wave = t >> 6;
    if (lane == 0) smem[wave] = (double)a;
    __syncthreads();
    if (t == 0) {
        double s = 0.0;
        #pragma unroll
        for (int w = 0; w < NTHREADS / 64; ++w) s += smem[w];
        partial[blockIdx.x] = s;
    }
}

__global__ __launch_bounds__(NTHREADS) void mtl_final_kernel(
    const double* __restrict__ partial, float* __restrict__ out, int nblocks, int B)
{
    double acc = 0.0;
    for (int i = threadIdx.x; i < nblocks; i += NTHREADS)
        acc += partial[i];
    #pragma unroll
    for (int off = 32; off > 0; off >>= 1)
        acc += __shfl_down(acc, off, 64);
    __shared__ double smem[NTHREADS / 64];
    const int lane = threadIdx.x & 63;
    const int wave = threadIdx.x >> 6;
    if (lane == 0) smem[wave] = acc;
    __syncthreads();
    if (threadIdx.x == 0) {
        double s = 0.0;
        #pragma unroll
        for (int w = 0; w < NTHREADS / 64; ++w) s += smem[w];
        out[0] = (float)(s / (double)B);
    }
}

extern "C" void kernel_launch(void* const* d_in, const int* in_sizes, int n_in,
                              void* d_out, int out_size, void* d_ws, size_t ws_size,
                              hipStream_t stream) {
    const float* pb = (const float*)d_in[0];
    const float* pt = (const float*)d_in[1];
    const float* ps = (const float*)d_in[2];
    const float* tb = (const float*)d_in[3];
    const float* tt = (const float*)d_in[4];
    const int*   ts = (const int*)d_in[5];
    float* out = (float*)d_out;
    const int B = in_sizes[0];

    double* partial = (double*)d_ws;  // NBLOCKS doubles = 16 KiB

    mtl_partial_kernel<<<NBLOCKS, NTHREADS, 0, stream>>>(pb, pt, ps, tb, tt, ts, partial, B);
    mtl_final_kernel<<<1, NTHREADS, 0, stream>>>(partial, out, NBLOCKS, B);
}